// Round 1
// baseline (922.532 us; speedup 1.0000x reference)
//
#include <hip/hip_runtime.h>
#include <math.h>

#define NLV 16
#define LOG2_T 19
#define T_SIZE (1u << LOG2_T)
#define T_MASK (T_SIZE - 1u)
#define P2 2654435761u
#define P3 805459861u

struct Scales { float s[NLV]; };

__global__ __launch_bounds__(256) void tcnn_fused_kernel(
    const float* __restrict__ x,
    const float* __restrict__ table,
    const float* __restrict__ W0, const float* __restrict__ b0,
    const float* __restrict__ W1, const float* __restrict__ b1,
    const float* __restrict__ W2, const float* __restrict__ b2,
    float* __restrict__ out, int N, Scales sc)
{
    int i = blockIdx.x * blockDim.x + threadIdx.x;
    if (i >= N) return;

    const float px = x[3 * (size_t)i + 0];
    const float py = x[3 * (size_t)i + 1];
    const float pz = x[3 * (size_t)i + 2];

    float enc[2 * NLV];

    #pragma unroll
    for (int l = 0; l < NLV; ++l) {
        const float s = sc.s[l];
        const float fx = px * s, fy = py * s, fz = pz * s;
        const float bx = floorf(fx), by = floorf(fy), bz = floorf(fz);
        const float rx = fx - bx, ry = fy - by, rz = fz - bz;
        const unsigned ix0 = (unsigned)bx, iy0 = (unsigned)by, iz0 = (unsigned)bz;
        // hash partial products (x uses prime 1)
        const unsigned hx0 = ix0,            hx1 = ix0 + 1u;
        const unsigned hy0 = iy0 * P2,       hy1 = (iy0 + 1u) * P2;
        const unsigned hz0 = iz0 * P3,       hz1 = (iz0 + 1u) * P3;
        const float* tl = table + (size_t)l * (size_t)T_SIZE * 2u;

        float f0 = 0.f, f1 = 0.f;
        const float wx0 = 1.f - rx, wy0 = 1.f - ry, wz0 = 1.f - rz;
        #pragma unroll
        for (int c = 0; c < 8; ++c) {
            unsigned h = ((c & 4) ? hx1 : hx0) ^ ((c & 2) ? hy1 : hy0) ^ ((c & 1) ? hz1 : hz0);
            h &= T_MASK;
            const float2 f = *(const float2*)(tl + 2u * (size_t)h);
            const float w = ((c & 4) ? rx : wx0) * ((c & 2) ? ry : wy0) * ((c & 1) ? rz : wz0);
            f0 += w * f.x;
            f1 += w * f.y;
        }
        enc[2 * l + 0] = f0;
        enc[2 * l + 1] = f1;
    }

    // --- tiny MLP, fp32 on VALU (no fp32 MFMA on CDNA4) ---
    float a0[16];
    #pragma unroll
    for (int j = 0; j < 16; ++j) {
        float s = b0[j];
        #pragma unroll
        for (int k = 0; k < 32; ++k) s += enc[k] * W0[j * 32 + k];
        a0[j] = fmaxf(s, 0.f);
    }
    float a1[16];
    #pragma unroll
    for (int j = 0; j < 16; ++j) {
        float s = b1[j];
        #pragma unroll
        for (int k = 0; k < 16; ++k) s += a0[k] * W1[j * 16 + k];
        a1[j] = fmaxf(s, 0.f);
    }
    float o[16];
    #pragma unroll
    for (int j = 0; j < 16; ++j) {
        float s = b2[j];
        #pragma unroll
        for (int k = 0; k < 16; ++k) s += a1[k] * W2[j * 16 + k];
        o[j] = s;
    }

    float4* o4 = (float4*)(out + 16 * (size_t)i);
    o4[0] = make_float4(o[0],  o[1],  o[2],  o[3]);
    o4[1] = make_float4(o[4],  o[5],  o[6],  o[7]);
    o4[2] = make_float4(o[8],  o[9],  o[10], o[11]);
    o4[3] = make_float4(o[12], o[13], o[14], o[15]);
}

extern "C" void kernel_launch(void* const* d_in, const int* in_sizes, int n_in,
                              void* d_out, int out_size, void* d_ws, size_t ws_size,
                              hipStream_t stream) {
    const float* x     = (const float*)d_in[0];
    const float* table = (const float*)d_in[1];
    const float* W0    = (const float*)d_in[2];
    const float* b0    = (const float*)d_in[3];
    const float* W1    = (const float*)d_in[4];
    const float* b1    = (const float*)d_in[5];
    const float* W2    = (const float*)d_in[6];
    const float* b2    = (const float*)d_in[7];
    float* out = (float*)d_out;

    const int N = in_sizes[0] / 3;

    Scales sc;
    const double pls = exp2(log2(2048.0 / 16.0) / 15.0);  // matches numpy double math
    for (int l = 0; l < NLV; ++l) sc.s[l] = (float)(16.0 * pow(pls, (double)l));

    const int block = 256;
    const int grid = (N + block - 1) / block;
    tcnn_fused_kernel<<<grid, block, 0, stream>>>(x, table, W0, b0, W1, b1, W2, b2,
                                                  out, N, sc);
}

// Round 2
// 611.958 us; speedup vs baseline: 1.5075x; 1.5075x over previous
//
#include <hip/hip_runtime.h>
#include <math.h>

#define NLV 16
#define LOG2_T 19
#define T_SIZE (1u << LOG2_T)
#define T_MASK (T_SIZE - 1u)
#define P2 2654435761u
#define P3 805459861u

typedef float vf2 __attribute__((ext_vector_type(2)));
typedef float vf4 __attribute__((ext_vector_type(4)));

struct Scales { float s[NLV]; };

__device__ __forceinline__ void enc_level(
    float px, float py, float pz, float s, const float* __restrict__ tl,
    float& f0, float& f1)
{
    const float fx = px * s, fy = py * s, fz = pz * s;
    const float bx = floorf(fx), by = floorf(fy), bz = floorf(fz);
    const float rx = fx - bx, ry = fy - by, rz = fz - bz;
    const unsigned ix0 = (unsigned)bx, iy0 = (unsigned)by, iz0 = (unsigned)bz;
    const unsigned hx0 = ix0,      hx1 = ix0 + 1u;
    const unsigned hy0 = iy0 * P2, hy1 = (iy0 + 1u) * P2;
    const unsigned hz0 = iz0 * P3, hz1 = (iz0 + 1u) * P3;
    const float wx0 = 1.f - rx, wy0 = 1.f - ry, wz0 = 1.f - rz;
    f0 = 0.f; f1 = 0.f;
    #pragma unroll
    for (int c = 0; c < 8; ++c) {
        unsigned h = ((c & 4) ? hx1 : hx0) ^ ((c & 2) ? hy1 : hy0) ^ ((c & 1) ? hz1 : hz0);
        h &= T_MASK;
        const vf2 f = *(const vf2*)(tl + 2u * (size_t)h);
        const float w = ((c & 4) ? rx : wx0) * ((c & 2) ? ry : wy0) * ((c & 1) ? rz : wz0);
        f0 += w * f[0];
        f1 += w * f[1];
    }
}

// Levels 0..4: working sets sum to ~2.6 MB -> co-resident in L2, fuse them.
__global__ __launch_bounds__(256) void encode_coarse_kernel(
    const float* __restrict__ x, const float* __restrict__ table,
    float* __restrict__ enc, int N, Scales sc)
{
    int i = blockIdx.x * 256 + threadIdx.x;
    if (i >= N) return;
    const float px = x[3 * (size_t)i + 0];
    const float py = x[3 * (size_t)i + 1];
    const float pz = x[3 * (size_t)i + 2];
    #pragma unroll
    for (int l = 0; l < 5; ++l) {
        float f0, f1;
        enc_level(px, py, pz, sc.s[l], table + (size_t)l * T_SIZE * 2u, f0, f1);
        vf2 v; v[0] = f0; v[1] = f1;
        __builtin_nontemporal_store(v, (vf2*)(enc + ((size_t)l * N + i) * 2u));
    }
}

// One fine level per launch: its 4 MiB table becomes resident in each XCD's L2.
__global__ __launch_bounds__(256) void encode_one_kernel(
    const float* __restrict__ x, const float* __restrict__ tl, float s,
    float* __restrict__ encl, int N)
{
    int i = blockIdx.x * 256 + threadIdx.x;
    if (i >= N) return;
    const float px = __builtin_nontemporal_load(x + 3 * (size_t)i + 0);
    const float py = __builtin_nontemporal_load(x + 3 * (size_t)i + 1);
    const float pz = __builtin_nontemporal_load(x + 3 * (size_t)i + 2);
    float f0, f1;
    enc_level(px, py, pz, s, tl, f0, f1);
    vf2 v; v[0] = f0; v[1] = f1;
    __builtin_nontemporal_store(v, (vf2*)(encl + (size_t)i * 2u));
}

__global__ __launch_bounds__(256) void mlp_kernel(
    const float* __restrict__ enc,
    const float* __restrict__ W0, const float* __restrict__ b0,
    const float* __restrict__ W1, const float* __restrict__ b1,
    const float* __restrict__ W2, const float* __restrict__ b2,
    float* __restrict__ out, int N)
{
    int i = blockIdx.x * 256 + threadIdx.x;
    if (i >= N) return;

    float e[32];
    #pragma unroll
    for (int l = 0; l < NLV; ++l) {
        vf2 v = __builtin_nontemporal_load((const vf2*)(enc + ((size_t)l * N + i) * 2u));
        e[2 * l + 0] = v[0];
        e[2 * l + 1] = v[1];
    }

    float a0[16];
    #pragma unroll
    for (int j = 0; j < 16; ++j) {
        float s = b0[j];
        #pragma unroll
        for (int k = 0; k < 32; ++k) s += e[k] * W0[j * 32 + k];
        a0[j] = fmaxf(s, 0.f);
    }
    float a1[16];
    #pragma unroll
    for (int j = 0; j < 16; ++j) {
        float s = b1[j];
        #pragma unroll
        for (int k = 0; k < 16; ++k) s += a0[k] * W1[j * 16 + k];
        a1[j] = fmaxf(s, 0.f);
    }
    float o[16];
    #pragma unroll
    for (int j = 0; j < 16; ++j) {
        float s = b2[j];
        #pragma unroll
        for (int k = 0; k < 16; ++k) s += a1[k] * W2[j * 16 + k];
        o[j] = s;
    }

    #pragma unroll
    for (int q = 0; q < 4; ++q) {
        vf4 v; v[0] = o[4*q]; v[1] = o[4*q+1]; v[2] = o[4*q+2]; v[3] = o[4*q+3];
        __builtin_nontemporal_store(v, (vf4*)(out + 16 * (size_t)i + 4 * q));
    }
}

// Fallback: round-0 fused kernel (used only if ws is too small for enc).
__global__ __launch_bounds__(256) void tcnn_fused_kernel(
    const float* __restrict__ x,
    const float* __restrict__ table,
    const float* __restrict__ W0, const float* __restrict__ b0,
    const float* __restrict__ W1, const float* __restrict__ b1,
    const float* __restrict__ W2, const float* __restrict__ b2,
    float* __restrict__ out, int N, Scales sc)
{
    int i = blockIdx.x * blockDim.x + threadIdx.x;
    if (i >= N) return;
    const float px = x[3 * (size_t)i + 0];
    const float py = x[3 * (size_t)i + 1];
    const float pz = x[3 * (size_t)i + 2];
    float e[32];
    #pragma unroll
    for (int l = 0; l < NLV; ++l) {
        float f0, f1;
        enc_level(px, py, pz, sc.s[l], table + (size_t)l * T_SIZE * 2u, f0, f1);
        e[2 * l] = f0; e[2 * l + 1] = f1;
    }
    float a0[16];
    #pragma unroll
    for (int j = 0; j < 16; ++j) {
        float s = b0[j];
        #pragma unroll
        for (int k = 0; k < 32; ++k) s += e[k] * W0[j * 32 + k];
        a0[j] = fmaxf(s, 0.f);
    }
    float a1[16];
    #pragma unroll
    for (int j = 0; j < 16; ++j) {
        float s = b1[j];
        #pragma unroll
        for (int k = 0; k < 16; ++k) s += a0[k] * W1[j * 16 + k];
        a1[j] = fmaxf(s, 0.f);
    }
    #pragma unroll
    for (int j = 0; j < 16; ++j) {
        float s = b2[j];
        #pragma unroll
        for (int k = 0; k < 16; ++k) s += a1[k] * W2[j * 16 + k];
        out[16 * (size_t)i + j] = s;
    }
}

extern "C" void kernel_launch(void* const* d_in, const int* in_sizes, int n_in,
                              void* d_out, int out_size, void* d_ws, size_t ws_size,
                              hipStream_t stream) {
    const float* x     = (const float*)d_in[0];
    const float* table = (const float*)d_in[1];
    const float* W0    = (const float*)d_in[2];
    const float* b0    = (const float*)d_in[3];
    const float* W1    = (const float*)d_in[4];
    const float* b1    = (const float*)d_in[5];
    const float* W2    = (const float*)d_in[6];
    const float* b2    = (const float*)d_in[7];
    float* out = (float*)d_out;

    const int N = in_sizes[0] / 3;

    Scales sc;
    const double pls = exp2(log2(2048.0 / 16.0) / 15.0);  // matches numpy double math
    for (int l = 0; l < NLV; ++l) sc.s[l] = (float)(16.0 * pow(pls, (double)l));

    const int block = 256;
    const int grid = (N + block - 1) / block;

    const size_t need = (size_t)N * 2u * NLV * sizeof(float);  // 128 MiB
    if (ws_size >= need) {
        float* enc = (float*)d_ws;
        encode_coarse_kernel<<<grid, block, 0, stream>>>(x, table, enc, N, sc);
        for (int l = 5; l < NLV; ++l) {
            encode_one_kernel<<<grid, block, 0, stream>>>(
                x, table + (size_t)l * T_SIZE * 2u, sc.s[l],
                enc + (size_t)l * (size_t)N * 2u, N);
        }
        mlp_kernel<<<grid, block, 0, stream>>>(enc, W0, b0, W1, b1, W2, b2, out, N);
    } else {
        tcnn_fused_kernel<<<grid, block, 0, stream>>>(x, table, W0, b0, W1, b1, W2, b2,
                                                      out, N, sc);
    }
}